// Round 11
// baseline (7328.836 us; speedup 1.0000x reference)
//
#include <hip/hip_runtime.h>

#define T_TOK 4096
#define HID   4096
#define IMD   11008

using f32x4  = __attribute__((ext_vector_type(4))) float;
using bf16x8 = __attribute__((ext_vector_type(8))) __bf16;
union FragCast { int4 i; bf16x8 b; };

__device__ __forceinline__ unsigned f2bf_bits(float f) {
  unsigned u = __float_as_uint(f);
  return (u + 0x7fffu + ((u >> 16) & 1u)) >> 16;   // RNE f32 -> bf16
}
__device__ __forceinline__ float bf2f(short s) {
  return __uint_as_float(((unsigned)(unsigned short)s) << 16);
}
__device__ __forceinline__ int4 cvt8(const float4 f0, const float4 f1) {
  int4 r;
  r.x = f2bf_bits(f0.x) | (f2bf_bits(f0.y) << 16);
  r.y = f2bf_bits(f0.z) | (f2bf_bits(f0.w) << 16);
  r.z = f2bf_bits(f1.x) | (f2bf_bits(f1.y) << 16);
  r.w = f2bf_bits(f1.z) | (f2bf_bits(f1.w) << 16);
  return r;
}
__device__ __forceinline__ void gload16(const void* g, void* l) {
  __builtin_amdgcn_global_load_lds(
      (__attribute__((address_space(1))) void*)g,
      (__attribute__((address_space(3))) void*)l, 16, 0, 0);
}

// ---------------------------------------------------------------- prep kernels
__global__ void cvt_pad(const float* __restrict__ in, short* __restrict__ out,
                        int C8, long ldin, long ldout) {
  long r = blockIdx.x;
  const float4* s = (const float4*)(in + r * ldin);
  int4* d = (int4*)(out + r * ldout);
  for (int c = threadIdx.x; c < C8; c += blockDim.x)
    d[c] = cvt8(s[2 * c], s[2 * c + 1]);
}

__global__ void build_wbT_pad(const float* __restrict__ wb,
                              short* __restrict__ out, int N, long ldout,
                              long K) {
  int n = blockIdx.x * blockDim.x + threadIdx.x;
  int ar = blockIdx.y;
  if (n < N) out[(long)n * ldout + K + ar] = (short)f2bf_bits(wb[(long)ar * N + n]);
}

__global__ void zero_band(short* out, long ld, long col0) {
  out[(long)blockIdx.x * ld + col0 + threadIdx.x] = 0;
}

// per-token rank projection: out[t][a*16+r] = mask * sum_h Abf[t][h]*wa[a][h][r]
template <int KD, int NOUT>
__global__ __launch_bounds__(256)
void lora_proj(const short* __restrict__ Abf, long ldA,
               const float* __restrict__ wa0, const float* __restrict__ wa1,
               const int* __restrict__ seg, short* out0, long ld0, short* out1,
               long ld1) {
  __shared__ __align__(16) short rowbuf[KD];
  __shared__ float part[NOUT][4][16];
  int t = blockIdx.x, tid = threadIdx.x;
  int a = seg[t];
  const int4* src = (const int4*)(Abf + (long)t * ldA);
  for (int c = tid; c < KD / 8; c += 256) ((int4*)rowbuf)[c] = src[c];
  __syncthreads();
  int w = tid >> 6, l = tid & 63;
  int r = l & 15, g = l >> 4;
  const int HW = KD / 4;
  float s0 = 0.f, s1 = 0.f;
  const float* p0 = wa0 + (long)a * KD * 16 + r;
  const float* p1 = (NOUT == 2) ? (wa1 + (long)a * KD * 16 + r) : nullptr;
  int h = w * HW + g;
  for (int k = 0; k < HW / 4; ++k, h += 4) {
    float xv = bf2f(rowbuf[h]);
    s0 = fmaf(xv, p0[(long)h * 16], s0);
    if (NOUT == 2) s1 = fmaf(xv, p1[(long)h * 16], s1);
  }
  s0 += __shfl_xor(s0, 16); s0 += __shfl_xor(s0, 32);
  if (NOUT == 2) { s1 += __shfl_xor(s1, 16); s1 += __shfl_xor(s1, 32); }
  if (l < 16) { part[0][w][r] = s0; if (NOUT == 2) part[1][w][r] = s1; }
  __syncthreads();
  if (tid < 64 * NOUT) {
    int m = tid >> 6, ar = tid & 63;
    float v = 0.f;
    if ((ar >> 4) == a) {
      int r2 = ar & 15;
      v = part[m][0][r2] + part[m][1][r2] + part[m][2][r2] + part[m][3][r2];
    }
    short b = (short)f2bf_bits(v);
    if (m == 0) out0[(long)t * ld0 + ar] = b;
    else        out1[(long)t * ld1 + ar] = b;
  }
}

// -------------------- FUSED gate+up GEMM: 256x256 tile, both B panels
// t[M][N] = silu(A@Bg^T) * (A@Bu^T), LoRA folded as TWO padded K-tail steps
// (band1 = xa_g|wbT_g|0, band2 = xa_u|0|wbT_u; ldK = K+128, NT = ldK/64).
// 8 waves (2M x 4N), per-wave 128x64 PER GEMM (acc 256 VGPR, lb(512,1)).
// LDS 128KB: A dbuf 2x32K @0/@32768, Bg @65536, Bu @98304 (single-buffered).
// Per K-step, 8 single-barrier phases {reads; stage; [wait]; bar; 16 MFMA}:
//  ph0 rd bFg+aFq0          ph4 rd bFu
//  ph1 rd aFq1, st Ah0(t+1) ph5 st Bu(t+1)
//  ph2 st Ah1(t+1)          ph6 -
//  ph3 st Bg(t+1) vmcnt(8)  ph7 vmcnt(4)
// Wait audit (12 ops/step, order Ah0,Ah1,Bg,Bu): ph3 queue =
// [Bu(t)4, A(t+1)4, Bg(t+1)4] -> vmcnt(8) confirms Bu(t) (read ph4);
// ph7 queue = [A(t+1)4, Bg(t+1)4, Bu(t+1)4] -> vmcnt(4) confirms A+Bg for
// next ph0. Never drains mid-loop. WAR: Bg overwrite (ph3) is 3 barriers
// after its read (ph0); Bu (ph5) 1 barrier after ph4 read; A(t+1) a full
// step after A(t-1)'s last read. Swizzle as R10 (source-side chunk XOR).
__global__ __launch_bounds__(512, 1)
void gemm_fused(const short* __restrict__ A, const short* __restrict__ Bg,
                const short* __restrict__ Bu, short* __restrict__ outT,
                int nby, long ldK, int NT, long ldo) {
  extern __shared__ __align__(16) char smem[];

  int nwg = gridDim.x;
  int orig = blockIdx.x;
  int q = nwg >> 3, rr = nwg & 7;
  int xcd = orig & 7, loc = orig >> 3;
  int swz = (xcd < rr ? xcd * (q + 1) : rr * (q + 1) + (xcd - rr) * q) + loc;
  int bx = swz & 15, by = swz >> 4;     // bx-fastest: B panels L2-resident
  long row0 = (long)bx * 256, col0 = (long)by * 256;

  int tid = threadIdx.x;
  int l = tid & 63, wid = tid >> 6;
  int wr = wid >> 2, wc = wid & 3;      // 2M x 4N waves, 128x64 each (per gemm)
  int lrow = l & 15, lhi = l >> 4, md = lrow & 7;

  const int rr0 = tid >> 3, cc0 = tid & 7;
  const short* pA  = A  + (row0 + rr0) * ldK + (cc0 ^ (rr0 & 7)) * 8;
  const short* pBg = Bg + (col0 + rr0) * ldK + (cc0 ^ (rr0 & 7)) * 8;
  const short* pBu = Bu + (col0 + rr0) * ldK + (cc0 ^ (rr0 & 7)) * 8;

  // chunk k (rows rr0+64k): src = p + 64k*ldK, LDS dst = base + tid*16 + 8192k
  auto stA_h = [&](int buf, int h, int kt) {
    char* d = smem + buf * 32768 + tid * 16;
    const short* s = pA + (long)kt * 64;
    gload16(s + (long)(2 * h) * 64 * ldK, d + (2 * h) * 8192);
    gload16(s + (long)(2 * h + 1) * 64 * ldK, d + (2 * h + 1) * 8192);
  };
  auto stB4 = [&](const short* p, char* base, int kt) {
    char* d = base + tid * 16;
    const short* s = p + (long)kt * 64;
    gload16(s, d);
    gload16(s + (long)64 * ldK, d + 8192);
    gload16(s + (long)128 * ldK, d + 16384);
    gload16(s + (long)192 * ldK, d + 24576);
  };

  f32x4 accg[8][4], accu[8][4];
  f32x4 zr = {0.f, 0.f, 0.f, 0.f};
#pragma unroll
  for (int mi = 0; mi < 8; ++mi)
#pragma unroll
    for (int ni = 0; ni < 4; ++ni) { accg[mi][ni] = zr; accu[mi][ni] = zr; }

  const int csel0 = (lhi ^ md) * 16;
  const int csel1 = ((4 + lhi) ^ md) * 16;

  bf16x8 aFq0[4][2], aFq1[4][2], bFg[4][2], bFu[4][2];

  auto readA8 = [&](const char* Ab, int qm, bf16x8 (&aF)[4][2]) {
#pragma unroll
    for (int mi = 0; mi < 4; ++mi) {
      const char* base = Ab + (wr * 128 + qm * 64 + mi * 16 + lrow) * 128;
      FragCast f0, f1;
      f0.i = *(const int4*)(base + csel0);
      f1.i = *(const int4*)(base + csel1);
      aF[mi][0] = f0.b; aF[mi][1] = f1.b;
    }
  };
  auto readB8 = [&](const char* Bb, bf16x8 (&bF)[4][2]) {
#pragma unroll
    for (int ni = 0; ni < 4; ++ni) {
      const char* base = Bb + (wc * 64 + ni * 16 + lrow) * 128;
      FragCast f0, f1;
      f0.i = *(const int4*)(base + csel0);
      f1.i = *(const int4*)(base + csel1);
      bF[ni][0] = f0.b; bF[ni][1] = f1.b;
    }
  };

#define CLU(ACC, QM, K, AF, BF)                                           \
  do {                                                                    \
    __builtin_amdgcn_s_setprio(1);                                        \
    _Pragma("unroll") for (int mi = 0; mi < 4; ++mi)                      \
        _Pragma("unroll") for (int ni = 0; ni < 4; ++ni)                  \
            ACC[(QM)*4 + mi][ni] = __builtin_amdgcn_mfma_f32_16x16x32_bf16( \
                AF[mi][K], BF[ni][K], ACC[(QM)*4 + mi][ni], 0, 0, 0);     \
    __builtin_amdgcn_s_setprio(0);                                        \
  } while (0)

#define BAR asm volatile("s_barrier" ::: "memory")

  // prologue: A(0), Bg(0), Bu(0); confirm A(0)+Bg(0), leave Bu(0) in flight
  stA_h(0, 0, 0); stA_h(0, 1, 0);
  stB4(pBg, smem + 65536, 0);
  stB4(pBu, smem + 98304, 0);
  asm volatile("s_waitcnt vmcnt(4)" ::: "memory");
  BAR;

#pragma unroll 1
  for (int t = 0; t < NT; ++t) {
    const char* Ab = smem + (t & 1) * 32768;
    int nb = (t + 1) & 1;
    bool st1 = (t + 1) < NT;
    // ph0
    readB8(smem + 65536, bFg);
    readA8(Ab, 0, aFq0);
    BAR; CLU(accg, 0, 0, aFq0, bFg);
    // ph1
    readA8(Ab, 1, aFq1);
    if (st1) stA_h(nb, 0, t + 1);
    BAR; CLU(accg, 0, 1, aFq0, bFg);
    // ph2
    if (st1) stA_h(nb, 1, t + 1);
    BAR; CLU(accg, 1, 0, aFq1, bFg);
    // ph3
    if (st1) {
      stB4(pBg, smem + 65536, t + 1);
      asm volatile("s_waitcnt vmcnt(8)" ::: "memory");
    } else {
      asm volatile("s_waitcnt vmcnt(0)" ::: "memory");
    }
    BAR; CLU(accg, 1, 1, aFq1, bFg);
    // ph4
    readB8(smem + 98304, bFu);
    BAR; CLU(accu, 0, 0, aFq0, bFu);
    // ph5
    if (st1) stB4(pBu, smem + 98304, t + 1);
    BAR; CLU(accu, 0, 1, aFq0, bFu);
    // ph6
    BAR; CLU(accu, 1, 0, aFq1, bFu);
    // ph7
    if (st1) asm volatile("s_waitcnt vmcnt(4)" ::: "memory");
    BAR; CLU(accu, 1, 1, aFq1, bFu);
  }

  // epilogue: t = silu(g)*u in regs; C/D layout col=lane&15, row=(l>>4)*4+reg
#pragma unroll
  for (int mi = 0; mi < 8; ++mi)
#pragma unroll
    for (int ni = 0; ni < 4; ++ni)
#pragma unroll
      for (int j = 0; j < 4; ++j) {
        long grow = row0 + wr * 128 + (mi >> 2) * 64 + (mi & 3) * 16 +
                    lhi * 4 + j;
        long gcol = col0 + wc * 64 + ni * 16 + lrow;
        float g = accg[(mi >> 2) * 4 + (mi & 3)][ni][j];
        float u = accu[(mi >> 2) * 4 + (mi & 3)][ni][j];
        float t2 = g * (1.f / (1.f + __expf(-g))) * u;
        outT[grow * ldo + gcol] = (short)f2bf_bits(t2);
      }
#undef CLU
#undef BAR
}

// --------------------- down GEMM: R10 4-phase kernel (measured ~312us)
__global__ __launch_bounds__(512, 2)
void gemm_down(const short* __restrict__ A, const short* __restrict__ B,
               float* outF, int nby, long ldK, int iters, long ldo) {
  extern __shared__ __align__(16) char smem[];

  int nwg = gridDim.x;
  int orig = blockIdx.x;
  int q = nwg >> 3, rr = nwg & 7;
  int xcd = orig & 7, loc = orig >> 3;
  int swz = (xcd < rr ? xcd * (q + 1) : rr * (q + 1) + (xcd - rr) * q) + loc;
  int by = swz % nby, bx = swz / nby;
  long row0 = (long)bx * 256, col0 = (long)by * 256;

  int tid = threadIdx.x;
  int l = tid & 63, wid = tid >> 6;
  int wr = wid >> 2, wc = wid & 3;
  int lrow = l & 15, lhi = l >> 4, md = lrow & 7;

  const short* aP[4]; const short* bP[4];
  int dst[4];
#pragma unroll
  for (int k = 0; k < 4; ++k) {
    int idx = tid + k * 512;
    int r = idx >> 3, c8 = idx & 7;
    aP[k] = A + (row0 + r) * ldK + (c8 ^ (r & 7)) * 8;
    bP[k] = B + (col0 + r) * ldK + (c8 ^ (r & 7)) * 8;
    dst[k] = idx * 16;
  }

  auto stageA_h = [&](int bi, int h) {
    char* d = smem + bi * 32768;
    gload16(aP[2 * h], d + dst[2 * h]);         aP[2 * h] += 64;
    gload16(aP[2 * h + 1], d + dst[2 * h + 1]); aP[2 * h + 1] += 64;
  };
  auto stageB_h = [&](int bi, int h) {
    char* d = smem + 98304 + bi * 32768;
    gload16(bP[2 * h], d + dst[2 * h]);         bP[2 * h] += 64;
    gload16(bP[2 * h + 1], d + dst[2 * h + 1]); bP[2 * h + 1] += 64;
  };

  f32x4 acc[8][4];
  f32x4 zr = {0.f, 0.f, 0.f, 0.f};
#pragma unroll
  for (int mi = 0; mi < 8; ++mi)
#pragma unroll
    for (int ni = 0; ni < 4; ++ni) acc[mi][ni] = zr;

  const int csel0 = (lhi ^ md) * 16;
  const int csel1 = ((4 + lhi) ^ md) * 16;

  stageA_h(0, 0); stageA_h(0, 1);
  stageB_h(0, 0); stageB_h(0, 1);
  stageA_h(1, 0); stageA_h(1, 1);
  asm volatile("s_waitcnt vmcnt(4)" ::: "memory");
  asm volatile("s_barrier" ::: "memory");

  int ca = 0;
#pragma unroll 1
  for (int t = 0; t < iters; ++t) {
    const char* Ab = smem + ca * 32768;
    const char* Bb = smem + 98304 + (t & 1) * 32768;
    int na2 = (ca >= 1) ? ca - 1 : 2;
    int nb1 = (t + 1) & 1;
    bf16x8 bF[4][2];

#pragma unroll
    for (int p = 0; p < 4; ++p) {
      if (p == 0) {
#pragma unroll
        for (int ni = 0; ni < 4; ++ni) {
          const char* base = Bb + (wc * 64 + ni * 16 + lrow) * 128;
          FragCast f0, f1;
          f0.i = *(const int4*)(base + csel0);
          f1.i = *(const int4*)(base + csel1);
          bF[ni][0] = f0.b; bF[ni][1] = f1.b;
        }
      }
      bf16x8 aF[2][2];
#pragma unroll
      for (int m2 = 0; m2 < 2; ++m2) {
        const char* base = Ab + (wr * 128 + p * 32 + m2 * 16 + lrow) * 128;
        FragCast f0, f1;
        f0.i = *(const int4*)(base + csel0);
        f1.i = *(const int4*)(base + csel1);
        aF[m2][0] = f0.b; aF[m2][1] = f1.b;
      }
      if (p == 0 && t + 1 < iters) stageB_h(nb1, 0);
      if (p == 1 && t + 1 < iters) stageB_h(nb1, 1);
      if (p == 2 && t + 2 < iters) stageA_h(na2, 0);
      if (p == 3) {
        if (t + 2 < iters) {
          stageA_h(na2, 1);
          asm volatile("s_waitcnt vmcnt(4)" ::: "memory");
        } else {
          asm volatile("s_waitcnt vmcnt(0)" ::: "memory");
        }
      }
      asm volatile("s_barrier" ::: "memory");
      __builtin_amdgcn_s_setprio(1);
#pragma unroll
      for (int k = 0; k < 2; ++k)
#pragma unroll
        for (int m2 = 0; m2 < 2; ++m2)
#pragma unroll
          for (int ni = 0; ni < 4; ++ni)
            acc[p * 2 + m2][ni] = __builtin_amdgcn_mfma_f32_16x16x32_bf16(
                aF[m2][k], bF[ni][k], acc[p * 2 + m2][ni], 0, 0, 0);
      __builtin_amdgcn_s_setprio(0);
      asm volatile("s_barrier" ::: "memory");
    }
    ca = (ca == 2) ? 0 : ca + 1;
  }

#pragma unroll
  for (int mi = 0; mi < 8; ++mi)
#pragma unroll
    for (int ni = 0; ni < 4; ++ni)
#pragma unroll
      for (int j = 0; j < 4; ++j) {
        long grow = row0 + wr * 128 + mi * 16 + lhi * 4 + j;
        long gcol = col0 + wc * 64 + ni * 16 + lrow;
        outF[grow * ldo + gcol] = acc[mi][ni][j];
      }
}

// ---------------------------------------------------------------- launcher
extern "C" void kernel_launch(void* const* d_in, const int* in_sizes, int n_in,
                              void* d_out, int out_size, void* d_ws,
                              size_t ws_size, hipStream_t stream) {
  const float* x       = (const float*)d_in[0];
  const float* gate_w  = (const float*)d_in[1];
  const float* up_w    = (const float*)d_in[2];
  const float* down_w  = (const float*)d_in[3];
  const float* gate_wa = (const float*)d_in[4];
  const float* gate_wb = (const float*)d_in[5];
  const float* up_wa   = (const float*)d_in[6];
  const float* up_wb   = (const float*)d_in[7];
  const float* down_wa = (const float*)d_in[8];
  const float* down_wb = (const float*)d_in[9];
  const int*   seg     = (const int*)d_in[10];

  // ldK gate/up = 4096+128 = 4224 (NT=66); down ld = 11008+64 = 11072 (173)
  char* ws = (char*)d_ws;
  short* xg_pad = (short*)(ws);                   // [4096][4224]  34.6 MB
  short* wA     = (short*)(ws + 34603008);        // gate_w pad -> down_w pad
  short* wB     = (short*)(ws + 127598592);       // up_w pad     93.0 MB
  short* t_pad  = (short*)(ws + 220594176);       // [4096][11072] 90.7 MB

  const int LDS_F = 131072;   // fused: A 2x32K + Bg 32K + Bu 32K
  const int LDS_D = 163840;   // down:  A 3x32K + B 2x32K
  hipFuncSetAttribute(reinterpret_cast<const void*>(&gemm_fused),
                      hipFuncAttributeMaxDynamicSharedMemorySize, LDS_F);
  hipFuncSetAttribute(reinterpret_cast<const void*>(&gemm_down),
                      hipFuncAttributeMaxDynamicSharedMemorySize, LDS_D);

  // bf16 padded operand build
  cvt_pad<<<T_TOK, 256, 0, stream>>>(x, xg_pad, 512, HID, 4224);
  cvt_pad<<<IMD, 256, 0, stream>>>(gate_w, wA, 512, HID, 4224);
  cvt_pad<<<IMD, 256, 0, stream>>>(up_w, wB, 512, HID, 4224);
  build_wbT_pad<<<dim3(43, 64), 256, 0, stream>>>(gate_wb, wA, IMD, 4224, 4096);
  build_wbT_pad<<<dim3(43, 64), 256, 0, stream>>>(up_wb, wB, IMD, 4224, 4160);
  zero_band<<<IMD, 64, 0, stream>>>(wA, 4224, 4160);   // gate: band2 = 0
  zero_band<<<IMD, 64, 0, stream>>>(wB, 4224, 4096);   // up:   band1 = 0
  lora_proj<HID, 2><<<T_TOK, 256, 0, stream>>>(
      xg_pad, 4224, gate_wa, up_wa, seg, xg_pad + 4096, 4224, xg_pad + 4160,
      4224);

  // fused gate+up: t_pad = silu(x@gw^T + lg) * (x@uw^T + lu)
  gemm_fused<<<16 * 43, 512, LDS_F, stream>>>(xg_pad, wA, wB, t_pad, 43, 4224,
                                              66, 11072);

  // down operand build (wA region free after fused GEMM)
  cvt_pad<<<T_TOK, 256, 0, stream>>>(down_w, wA, 1376, IMD, 11072);
  build_wbT_pad<<<dim3(16, 64), 256, 0, stream>>>(down_wb, wA, HID, 11072,
                                                  IMD);
  lora_proj<IMD, 1><<<T_TOK, 256, 0, stream>>>(
      t_pad, 11072, down_wa, nullptr, seg, t_pad + IMD, 11072, nullptr, 64);

  // down: out = t @ down_w^T + lora   [M=4096, N=4096, K'=11072]
  gemm_down<<<16 * 16, 512, LDS_D, stream>>>(t_pad, wA, (float*)d_out, 16,
                                             11072, 173, 4096);
}

// Round 12
// 1649.943 us; speedup vs baseline: 4.4419x; 4.4419x over previous
//
#include <hip/hip_runtime.h>

#define T_TOK 4096
#define HID   4096
#define IMD   11008

using f32x4  = __attribute__((ext_vector_type(4))) float;
using bf16x8 = __attribute__((ext_vector_type(8))) __bf16;
union FragCast { int4 i; bf16x8 b; };

__device__ __forceinline__ unsigned f2bf_bits(float f) {
  unsigned u = __float_as_uint(f);
  return (u + 0x7fffu + ((u >> 16) & 1u)) >> 16;   // RNE f32 -> bf16
}
__device__ __forceinline__ float bf2f(short s) {
  return __uint_as_float(((unsigned)(unsigned short)s) << 16);
}
__device__ __forceinline__ int4 cvt8(const float4 f0, const float4 f1) {
  int4 r;
  r.x = f2bf_bits(f0.x) | (f2bf_bits(f0.y) << 16);
  r.y = f2bf_bits(f0.z) | (f2bf_bits(f0.w) << 16);
  r.z = f2bf_bits(f1.x) | (f2bf_bits(f1.y) << 16);
  r.w = f2bf_bits(f1.z) | (f2bf_bits(f1.w) << 16);
  return r;
}
__device__ __forceinline__ void gload16(const void* g, void* l) {
  __builtin_amdgcn_global_load_lds(
      (__attribute__((address_space(1))) void*)g,
      (__attribute__((address_space(3))) void*)l, 16, 0, 0);
}

// ---------------------------------------------------------------- prep kernels
// convert C8 chunks (of 8 f32) per row; chunks [C8,CT) write zeros (pad tail)
__global__ void cvt_pad(const float* __restrict__ in, short* __restrict__ out,
                        int C8, int CT, long ldin, long ldout) {
  long r = blockIdx.x;
  const float4* s = (const float4*)(in + r * ldin);
  int4* d = (int4*)(out + r * ldout);
  for (int c = threadIdx.x; c < CT; c += blockDim.x)
    d[c] = (c < C8) ? cvt8(s[2 * c], s[2 * c + 1]) : int4{0, 0, 0, 0};
}

__global__ void build_wbT_pad(const float* __restrict__ wb,
                              short* __restrict__ out, int N, long ldout,
                              long K) {
  int n = blockIdx.x * blockDim.x + threadIdx.x;
  int ar = blockIdx.y;
  if (n < N) out[(long)n * ldout + K + ar] = (short)f2bf_bits(wb[(long)ar * N + n]);
}

// per-token rank projection: out[t][a*16+r] = mask * sum_h Abf[t][h]*wa[a][h][r]
template <int KD, int NOUT>
__global__ __launch_bounds__(256)
void lora_proj(const short* __restrict__ Abf, long ldA,
               const float* __restrict__ wa0, const float* __restrict__ wa1,
               const int* __restrict__ seg, short* out0, long ld0, short* out1,
               long ld1) {
  __shared__ __align__(16) short rowbuf[KD];
  __shared__ float part[NOUT][4][16];
  int t = blockIdx.x, tid = threadIdx.x;
  int a = seg[t];
  const int4* src = (const int4*)(Abf + (long)t * ldA);
  for (int c = tid; c < KD / 8; c += 256) ((int4*)rowbuf)[c] = src[c];
  __syncthreads();
  int w = tid >> 6, l = tid & 63;
  int r = l & 15, g = l >> 4;
  const int HW = KD / 4;
  float s0 = 0.f, s1 = 0.f;
  const float* p0 = wa0 + (long)a * KD * 16 + r;
  const float* p1 = (NOUT == 2) ? (wa1 + (long)a * KD * 16 + r) : nullptr;
  int h = w * HW + g;
  for (int k = 0; k < HW / 4; ++k, h += 4) {
    float xv = bf2f(rowbuf[h]);
    s0 = fmaf(xv, p0[(long)h * 16], s0);
    if (NOUT == 2) s1 = fmaf(xv, p1[(long)h * 16], s1);
  }
  s0 += __shfl_xor(s0, 16); s0 += __shfl_xor(s0, 32);
  if (NOUT == 2) { s1 += __shfl_xor(s1, 16); s1 += __shfl_xor(s1, 32); }
  if (l < 16) { part[0][w][r] = s0; if (NOUT == 2) part[1][w][r] = s1; }
  __syncthreads();
  if (tid < 64 * NOUT) {
    int m = tid >> 6, ar = tid & 63;
    float v = 0.f;
    if ((ar >> 4) == a) {
      int r2 = ar & 15;
      v = part[m][0][r2] + part[m][1][r2] + part[m][2][r2] + part[m][3][r2];
    }
    short b = (short)f2bf_bits(v);
    if (m == 0) out0[(long)t * ld0 + ar] = b;
    else        out1[(long)t * ld1 + ar] = b;
  }
}

// -------------- PERSISTENT gate/up GEMM: R10 4-phase schedule, 1 block/CU
// Grid = 256 (1/CU). Each block owns tiles {loc, loc+32, loc+64} of its XCD's
// contiguous 86-tile range (bx-fastest: B col-panel L2-resident, R10's win).
// Per tile: R10's proven 4-phase/K-step A3/B2 pipeline (verbatim schedule +
// wait audit; tail self-drains via vmcnt(0) at t=iters-2). Between tiles the
// NEXT tile's 12-load prologue is issued BEFORE the current epilogue stores,
// so the HBM load round-trip hides under the store drain; next tile entry
// does vmcnt(4)+barrier (queue = [12 loads, stores...] -> confirms A(0),B(0),
// leaves A(1) + <=4 stores in flight). Eliminates block launch/teardown and
// lockstep round boundaries (R11 theory: per-block fixed cost x2.69).
template <int MODE>  // 0: bf16 store; 1: silu(gbuf)*acc -> bf16 in-place
__global__ __launch_bounds__(512, 2)
void gemm_gu(const short* __restrict__ A, const short* __restrict__ B,
             const short* __restrict__ gbuf, short* __restrict__ outB,
             int tilesPerXcd, long ldK, int iters, long ldo) {
  extern __shared__ __align__(16) char smem[];
  // A bufs: 3 x 32KB at 0; B bufs: 2 x 32KB at 98304.

  int xcd = blockIdx.x & 7, loc = blockIdx.x >> 3;
  int tid = threadIdx.x;
  int l = tid & 63, wid = tid >> 6;
  int wr = wid >> 2, wc = wid & 3;      // 2M x 4N waves, 128x64 each
  int lrow = l & 15, lhi = l >> 4, md = lrow & 7;
  const int rr0 = tid >> 3;
  const long cOff = (long)(((tid & 7) ^ (rr0 & 7)) * 8);

  const int csel0 = (lhi ^ md) * 16;
  const int csel1 = ((4 + lhi) ^ md) * 16;

  const short* pA; const short* pB; long row0, col0;
  auto setTile = [&](int idxInXcd) {
    int gt = xcd * tilesPerXcd + idxInXcd;
    row0 = (long)(gt & 15) * 256;
    col0 = (long)(gt >> 4) * 256;
    pA = A + (row0 + rr0) * ldK + cOff;
    pB = B + (col0 + rr0) * ldK + cOff;
  };
  // stage half-tile h of K-tile kt (2 x gload16); dst chunks 2h, 2h+1
  auto stA = [&](int bi, int h, int kt) {
    char* d = smem + bi * 32768 + tid * 16;
    const short* s = pA + (long)kt * 64 + (long)(2 * h) * 64 * ldK;
    gload16(s, d + (2 * h) * 8192);
    gload16(s + (long)64 * ldK, d + (2 * h + 1) * 8192);
  };
  auto stB = [&](int bi, int h, int kt) {
    char* d = smem + 98304 + bi * 32768 + tid * 16;
    const short* s = pB + (long)kt * 64 + (long)(2 * h) * 64 * ldK;
    gload16(s, d + (2 * h) * 8192);
    gload16(s + (long)64 * ldK, d + (2 * h + 1) * 8192);
  };
  auto prologue = [&]() {
    stA(0, 0, 0); stA(0, 1, 0);
    stB(0, 0, 0); stB(0, 1, 0);
    stA(1, 0, 1); stA(1, 1, 1);    // queue: [A0(4), B0(4), A1(4)]
  };

  f32x4 zr = {0.f, 0.f, 0.f, 0.f};

  int r = loc;
  setTile(r);
  prologue();

  while (true) {
    f32x4 acc[8][4];
#pragma unroll
    for (int mi = 0; mi < 8; ++mi)
#pragma unroll
      for (int ni = 0; ni < 4; ++ni) acc[mi][ni] = zr;

    asm volatile("s_waitcnt vmcnt(4)" ::: "memory");  // A(0),B(0) landed
    asm volatile("s_barrier" ::: "memory");

    int ca = 0;
#pragma unroll 1
    for (int t = 0; t < iters; ++t) {
      const char* Ab = smem + ca * 32768;
      const char* Bb = smem + 98304 + (t & 1) * 32768;
      int na2 = (ca >= 1) ? ca - 1 : 2;   // (ca+2)%3: buffer for A(t+2)
      int nb1 = (t + 1) & 1;
      bf16x8 bF[4][2];

#pragma unroll
      for (int p = 0; p < 4; ++p) {
        if (p == 0) {
#pragma unroll
          for (int ni = 0; ni < 4; ++ni) {
            const char* base = Bb + (wc * 64 + ni * 16 + lrow) * 128;
            FragCast f0, f1;
            f0.i = *(const int4*)(base + csel0);
            f1.i = *(const int4*)(base + csel1);
            bF[ni][0] = f0.b; bF[ni][1] = f1.b;
          }
        }
        bf16x8 aF[2][2];
#pragma unroll
        for (int m2 = 0; m2 < 2; ++m2) {
          const char* base = Ab + (wr * 128 + p * 32 + m2 * 16 + lrow) * 128;
          FragCast f0, f1;
          f0.i = *(const int4*)(base + csel0);
          f1.i = *(const int4*)(base + csel1);
          aF[m2][0] = f0.b; aF[m2][1] = f1.b;
        }
        if (p == 0 && t + 1 < iters) stB(nb1, 0, t + 1);
        if (p == 1 && t + 1 < iters) stB(nb1, 1, t + 1);
        if (p == 2 && t + 2 < iters) stA(na2, 0, t + 2);
        if (p == 3) {
          if (t + 2 < iters) {
            stA(na2, 1, t + 2);
            asm volatile("s_waitcnt vmcnt(4)" ::: "memory");
          } else {
            asm volatile("s_waitcnt vmcnt(0)" ::: "memory");
          }
        }
        asm volatile("s_barrier" ::: "memory");
        __builtin_amdgcn_s_setprio(1);
#pragma unroll
        for (int k = 0; k < 2; ++k)
#pragma unroll
          for (int m2 = 0; m2 < 2; ++m2)
#pragma unroll
            for (int ni = 0; ni < 4; ++ni)
              acc[p * 2 + m2][ni] = __builtin_amdgcn_mfma_f32_16x16x32_bf16(
                  aF[m2][k], bF[ni][k], acc[p * 2 + m2][ni], 0, 0, 0);
        __builtin_amdgcn_s_setprio(0);
        asm volatile("s_barrier" ::: "memory");
      }
      ca = (ca == 2) ? 0 : ca + 1;
    }

    // chain: issue next tile's prologue BEFORE epilogue stores
    long crow = row0, ccol = col0;
    r += 32;
    bool hasNext = (r < tilesPerXcd);
    if (hasNext) { setTile(r); prologue(); }

    // epilogue: C/D layout col=lane&15, row=(lane>>4)*4+reg  [m89]
#pragma unroll
    for (int mi = 0; mi < 8; ++mi)
#pragma unroll
      for (int ni = 0; ni < 4; ++ni)
#pragma unroll
        for (int j = 0; j < 4; ++j) {
          long grow = crow + wr * 128 + mi * 16 + lhi * 4 + j;
          long gcol = ccol + wc * 64 + ni * 16 + lrow;
          long idx = grow * ldo + gcol;
          float v = acc[mi][ni][j];
          if constexpr (MODE == 0) {
            outB[idx] = (short)f2bf_bits(v);
          } else {
            float g = bf2f(gbuf[idx]);
            float t2 = g * (1.f / (1.f + __expf(-g))) * v;   // silu(g)*u
            outB[idx] = (short)f2bf_bits(t2);
          }
        }
    if (!hasNext) break;
  }
}

// --------------------- down GEMM: R10 4-phase kernel (1 block/CU, proven)
__global__ __launch_bounds__(512, 2)
void gemm_down(const short* __restrict__ A, const short* __restrict__ B,
               float* outF, int nby, long ldK, int iters, long ldo) {
  extern __shared__ __align__(16) char smem[];

  int nwg = gridDim.x;
  int orig = blockIdx.x;
  int q = nwg >> 3, rr = nwg & 7;
  int xcd = orig & 7, loc = orig >> 3;
  int swz = (xcd < rr ? xcd * (q + 1) : rr * (q + 1) + (xcd - rr) * q) + loc;
  int by = swz % nby, bx = swz / nby;
  long row0 = (long)bx * 256, col0 = (long)by * 256;

  int tid = threadIdx.x;
  int l = tid & 63, wid = tid >> 6;
  int wr = wid >> 2, wc = wid & 3;
  int lrow = l & 15, lhi = l >> 4, md = lrow & 7;

  const short* aP[4]; const short* bP[4];
  int dst[4];
#pragma unroll
  for (int k = 0; k < 4; ++k) {
    int idx = tid + k * 512;
    int r = idx >> 3, c8 = idx & 7;
    aP[k] = A + (row0 + r) * ldK + (c8 ^ (r & 7)) * 8;
    bP[k] = B + (col0 + r) * ldK + (c8 ^ (r & 7)) * 8;
    dst[k] = idx * 16;
  }

  auto stageA_h = [&](int bi, int h) {
    char* d = smem + bi * 32768;
    gload16(aP[2 * h], d + dst[2 * h]);         aP[2 * h] += 64;
    gload16(aP[2 * h + 1], d + dst[2 * h + 1]); aP[2 * h + 1] += 64;
  };
  auto stageB_h = [&](int bi, int h) {
    char* d = smem + 98304 + bi * 32768;
    gload16(bP[2 * h], d + dst[2 * h]);         bP[2 * h] += 64;
    gload16(bP[2 * h + 1], d + dst[2 * h + 1]); bP[2 * h + 1] += 64;
  };

  f32x4 acc[8][4];
  f32x4 zr = {0.f, 0.f, 0.f, 0.f};
#pragma unroll
  for (int mi = 0; mi < 8; ++mi)
#pragma unroll
    for (int ni = 0; ni < 4; ++ni) acc[mi][ni] = zr;

  const int csel0 = (lhi ^ md) * 16;
  const int csel1 = ((4 + lhi) ^ md) * 16;

  stageA_h(0, 0); stageA_h(0, 1);
  stageB_h(0, 0); stageB_h(0, 1);
  stageA_h(1, 0); stageA_h(1, 1);
  asm volatile("s_waitcnt vmcnt(4)" ::: "memory");
  asm volatile("s_barrier" ::: "memory");

  int ca = 0;
#pragma unroll 1
  for (int t = 0; t < iters; ++t) {
    const char* Ab = smem + ca * 32768;
    const char* Bb = smem + 98304 + (t & 1) * 32768;
    int na2 = (ca >= 1) ? ca - 1 : 2;
    int nb1 = (t + 1) & 1;
    bf16x8 bF[4][2];

#pragma unroll
    for (int p = 0; p < 4; ++p) {
      if (p == 0) {
#pragma unroll
        for (int ni = 0; ni < 4; ++ni) {
          const char* base = Bb + (wc * 64 + ni * 16 + lrow) * 128;
          FragCast f0, f1;
          f0.i = *(const int4*)(base + csel0);
          f1.i = *(const int4*)(base + csel1);
          bF[ni][0] = f0.b; bF[ni][1] = f1.b;
        }
      }
      bf16x8 aF[2][2];
#pragma unroll
      for (int m2 = 0; m2 < 2; ++m2) {
        const char* base = Ab + (wr * 128 + p * 32 + m2 * 16 + lrow) * 128;
        FragCast f0, f1;
        f0.i = *(const int4*)(base + csel0);
        f1.i = *(const int4*)(base + csel1);
        aF[m2][0] = f0.b; aF[m2][1] = f1.b;
      }
      if (p == 0 && t + 1 < iters) stageB_h(nb1, 0);
      if (p == 1 && t + 1 < iters) stageB_h(nb1, 1);
      if (p == 2 && t + 2 < iters) stageA_h(na2, 0);
      if (p == 3) {
        if (t + 2 < iters) {
          stageA_h(na2, 1);
          asm volatile("s_waitcnt vmcnt(4)" ::: "memory");
        } else {
          asm volatile("s_waitcnt vmcnt(0)" ::: "memory");
        }
      }
      asm volatile("s_barrier" ::: "memory");
      __builtin_amdgcn_s_setprio(1);
#pragma unroll
      for (int k = 0; k < 2; ++k)
#pragma unroll
        for (int m2 = 0; m2 < 2; ++m2)
#pragma unroll
          for (int ni = 0; ni < 4; ++ni)
            acc[p * 2 + m2][ni] = __builtin_amdgcn_mfma_f32_16x16x32_bf16(
                aF[m2][k], bF[ni][k], acc[p * 2 + m2][ni], 0, 0, 0);
      __builtin_amdgcn_s_setprio(0);
      asm volatile("s_barrier" ::: "memory");
    }
    ca = (ca == 2) ? 0 : ca + 1;
  }

#pragma unroll
  for (int mi = 0; mi < 8; ++mi)
#pragma unroll
    for (int ni = 0; ni < 4; ++ni)
#pragma unroll
      for (int j = 0; j < 4; ++j) {
        long grow = row0 + wr * 128 + mi * 16 + lhi * 4 + j;
        long gcol = col0 + wc * 64 + ni * 16 + lrow;
        outF[grow * ldo + gcol] = acc[mi][ni][j];
      }
}

// ---------------------------------------------------------------- launcher
extern "C" void kernel_launch(void* const* d_in, const int* in_sizes, int n_in,
                              void* d_out, int out_size, void* d_ws,
                              size_t ws_size, hipStream_t stream) {
  const float* x       = (const float*)d_in[0];
  const float* gate_w  = (const float*)d_in[1];
  const float* up_w    = (const float*)d_in[2];
  const float* down_w  = (const float*)d_in[3];
  const float* gate_wa = (const float*)d_in[4];
  const float* gate_wb = (const float*)d_in[5];
  const float* up_wa   = (const float*)d_in[6];
  const float* up_wb   = (const float*)d_in[7];
  const float* down_wa = (const float*)d_in[8];
  const float* down_wb = (const float*)d_in[9];
  const int*   seg     = (const int*)d_in[10];

  // ldK gate/up = 4096+128 = 4224 (iters=66); down ld = 11008+64 = 11072 (173)
  char* ws = (char*)d_ws;
  short* xg_pad = (short*)(ws);                   // [4096][4224]  34.6 MB
  short* wA     = (short*)(ws + 34603008);        // gate_w pad -> down_w pad
  short* wB     = (short*)(ws + 127598592);       // up_w pad     93.0 MB
  short* t_pad  = (short*)(ws + 220594176);       // [4096][11072] 90.7 MB

  const int LDS_G = 163840;   // A 3x32K + B 2x32K
  hipFuncSetAttribute(reinterpret_cast<const void*>(&gemm_gu<0>),
                      hipFuncAttributeMaxDynamicSharedMemorySize, LDS_G);
  hipFuncSetAttribute(reinterpret_cast<const void*>(&gemm_gu<1>),
                      hipFuncAttributeMaxDynamicSharedMemorySize, LDS_G);
  hipFuncSetAttribute(reinterpret_cast<const void*>(&gemm_down),
                      hipFuncAttributeMaxDynamicSharedMemorySize, LDS_G);

  // bf16 padded operand build (cvt_pad zero-fills the 128-col LoRA tail of
  // the weight matrices; build_wbT then overwrites its 64-col band)
  cvt_pad<<<T_TOK, 256, 0, stream>>>(x, xg_pad, 512, 512, HID, 4224);
  cvt_pad<<<IMD, 256, 0, stream>>>(gate_w, wA, 512, 528, HID, 4224);
  cvt_pad<<<IMD, 256, 0, stream>>>(up_w, wB, 512, 528, HID, 4224);
  build_wbT_pad<<<dim3(43, 64), 256, 0, stream>>>(gate_wb, wA, IMD, 4224, 4096);
  build_wbT_pad<<<dim3(43, 64), 256, 0, stream>>>(up_wb, wB, IMD, 4224, 4160);
  lora_proj<HID, 2><<<T_TOK, 256, 0, stream>>>(
      xg_pad, 4224, gate_wa, up_wa, seg, xg_pad + 4096, 4224, xg_pad + 4160,
      4224);

  // gate (persistent, 1 block/CU): t_pad = x @ gate_w^T + lora_g
  // LoRA = 2 padded K-tail steps (band1 = xa_g|wbT_g|0, band2 = xa_u|0|wbT_u;
  // gate's band2 contributes xa_u * 0 = 0; up's band1 contributes 0).
  gemm_gu<0><<<256, 512, LDS_G, stream>>>(xg_pad, wA, nullptr, t_pad,
                                          86, 4224, 66, 11072);
  // up (persistent): t_pad = silu(t_pad) * (x @ up_w^T + lora_u), in place
  gemm_gu<1><<<256, 512, LDS_G, stream>>>(xg_pad, wB, t_pad, t_pad,
                                          86, 4224, 66, 11072);

  // down operand build (wA region free after gate GEMM)
  cvt_pad<<<T_TOK, 256, 0, stream>>>(down_w, wA, 1376, 1376, IMD, 11072);
  build_wbT_pad<<<dim3(16, 64), 256, 0, stream>>>(down_wb, wA, HID, 11072,
                                                  IMD);
  lora_proj<IMD, 1><<<T_TOK, 256, 0, stream>>>(
      t_pad, 11072, down_wa, nullptr, seg, t_pad + IMD, 11072, nullptr, 64);

  // down: out = t @ down_w^T + lora   [M=4096, N=4096, K'=11072]
  gemm_down<<<16 * 16, 512, LDS_G, stream>>>(t_pad, wA, (float*)d_out, 16,
                                             11072, 173, 4096);
}

// Round 13
// 1589.314 us; speedup vs baseline: 4.6113x; 1.0381x over previous
//
#include <hip/hip_runtime.h>

#define T_TOK 4096
#define HID   4096
#define IMD   11008

using f32x4  = __attribute__((ext_vector_type(4))) float;
using bf16x8 = __attribute__((ext_vector_type(8))) __bf16;
union FragCast { int4 i; bf16x8 b; };

__device__ __forceinline__ unsigned f2bf_bits(float f) {
  unsigned u = __float_as_uint(f);
  return (u + 0x7fffu + ((u >> 16) & 1u)) >> 16;   // RNE f32 -> bf16
}
__device__ __forceinline__ float bf2f(short s) {
  return __uint_as_float(((unsigned)(unsigned short)s) << 16);
}
__device__ __forceinline__ int4 cvt8(const float4 f0, const float4 f1) {
  int4 r;
  r.x = f2bf_bits(f0.x) | (f2bf_bits(f0.y) << 16);
  r.y = f2bf_bits(f0.z) | (f2bf_bits(f0.w) << 16);
  r.z = f2bf_bits(f1.x) | (f2bf_bits(f1.y) << 16);
  r.w = f2bf_bits(f1.z) | (f2bf_bits(f1.w) << 16);
  return r;
}
__device__ __forceinline__ void gload16(const void* g, void* l) {
  __builtin_amdgcn_global_load_lds(
      (__attribute__((address_space(1))) void*)g,
      (__attribute__((address_space(3))) void*)l, 16, 0, 0);
}

// ---------------------------------------------------------------- prep kernels
// convert C8 chunks (of 8 f32) per row; chunks [C8,CT) write zeros (pad tail)
__global__ void cvt_pad(const float* __restrict__ in, short* __restrict__ out,
                        int C8, int CT, long ldin, long ldout) {
  long r = blockIdx.x;
  const float4* s = (const float4*)(in + r * ldin);
  int4* d = (int4*)(out + r * ldout);
  for (int c = threadIdx.x; c < CT; c += blockDim.x)
    d[c] = (c < C8) ? cvt8(s[2 * c], s[2 * c + 1]) : int4{0, 0, 0, 0};
}

__global__ void build_wbT_pad(const float* __restrict__ wb,
                              short* __restrict__ out, int N, long ldout,
                              long K) {
  int n = blockIdx.x * blockDim.x + threadIdx.x;
  int ar = blockIdx.y;
  if (n < N) out[(long)n * ldout + K + ar] = (short)f2bf_bits(wb[(long)ar * N + n]);
}

// per-token rank projection: out[t][a*16+r] = mask * sum_h Abf[t][h]*wa[a][h][r]
template <int KD, int NOUT>
__global__ __launch_bounds__(256)
void lora_proj(const short* __restrict__ Abf, long ldA,
               const float* __restrict__ wa0, const float* __restrict__ wa1,
               const int* __restrict__ seg, short* out0, long ld0, short* out1,
               long ld1) {
  __shared__ __align__(16) short rowbuf[KD];
  __shared__ float part[NOUT][4][16];
  int t = blockIdx.x, tid = threadIdx.x;
  int a = seg[t];
  const int4* src = (const int4*)(Abf + (long)t * ldA);
  for (int c = tid; c < KD / 8; c += 256) ((int4*)rowbuf)[c] = src[c];
  __syncthreads();
  int w = tid >> 6, l = tid & 63;
  int r = l & 15, g = l >> 4;
  const int HW = KD / 4;
  float s0 = 0.f, s1 = 0.f;
  const float* p0 = wa0 + (long)a * KD * 16 + r;
  const float* p1 = (NOUT == 2) ? (wa1 + (long)a * KD * 16 + r) : nullptr;
  int h = w * HW + g;
  for (int k = 0; k < HW / 4; ++k, h += 4) {
    float xv = bf2f(rowbuf[h]);
    s0 = fmaf(xv, p0[(long)h * 16], s0);
    if (NOUT == 2) s1 = fmaf(xv, p1[(long)h * 16], s1);
  }
  s0 += __shfl_xor(s0, 16); s0 += __shfl_xor(s0, 32);
  if (NOUT == 2) { s1 += __shfl_xor(s1, 16); s1 += __shfl_xor(s1, 32); }
  if (l < 16) { part[0][w][r] = s0; if (NOUT == 2) part[1][w][r] = s1; }
  __syncthreads();
  if (tid < 64 * NOUT) {
    int m = tid >> 6, ar = tid & 63;
    float v = 0.f;
    if ((ar >> 4) == a) {
      int r2 = ar & 15;
      v = part[m][0][r2] + part[m][1][r2] + part[m][2][r2] + part[m][3][r2];
    }
    short b = (short)f2bf_bits(v);
    if (m == 0) out0[(long)t * ld0 + ar] = b;
    else        out1[(long)t * ld1 + ar] = b;
  }
}

// -------------- PERSISTENT gate/up GEMM: 4-phase, SINGLE barrier per phase
// R12 kernel with the post-MFMA barrier DELETED (8 -> 4 barriers/iter).
// Phase = [ds_reads | stage | (counted vmcnt at ph3) | BAR | 16 MFMA].
// Waves may skew by <=1 phase past the MFMA cluster -> one wave's ds_read/
// stage overlaps other waves' MFMA (LDS pipe || matrix pipe, the missing
// overlap: R12 measured ~6100 cyc/iter = LDS 3100 + MFMA 2060 + VALU 1000
// run SEQUENTIALLY under 2-barrier lockstep).
// Safety: [vmcnt(4); BAR] is still a collective confirm (each wave's count
// precedes the barrier). WAR: B(t&1) re-staged at t+1/ph0 is after BAR(t/ph3),
// and every wave's bF(t) LDS reads completed before its own ph0 MFMA; A-ring
// slot overwrites trail last reads by >=4 BARs. Skew bound = 1 phase (BAR
// each phase). Same argument at the tile-chain boundary.
template <int MODE>  // 0: bf16 store; 1: silu(gbuf)*acc -> bf16 in-place
__global__ __launch_bounds__(512, 2)
void gemm_gu(const short* __restrict__ A, const short* __restrict__ B,
             const short* __restrict__ gbuf, short* __restrict__ outB,
             int tilesPerXcd, long ldK, int iters, long ldo) {
  extern __shared__ __align__(16) char smem[];
  // A bufs: 3 x 32KB at 0; B bufs: 2 x 32KB at 98304.

  int xcd = blockIdx.x & 7, loc = blockIdx.x >> 3;
  int tid = threadIdx.x;
  int l = tid & 63, wid = tid >> 6;
  int wr = wid >> 2, wc = wid & 3;      // 2M x 4N waves, 128x64 each
  int lrow = l & 15, lhi = l >> 4, md = lrow & 7;
  const int rr0 = tid >> 3;
  const long cOff = (long)(((tid & 7) ^ (rr0 & 7)) * 8);

  const int csel0 = (lhi ^ md) * 16;
  const int csel1 = ((4 + lhi) ^ md) * 16;

  const short* pA; const short* pB; long row0, col0;
  auto setTile = [&](int idxInXcd) {
    int gt = xcd * tilesPerXcd + idxInXcd;
    row0 = (long)(gt & 15) * 256;
    col0 = (long)(gt >> 4) * 256;
    pA = A + (row0 + rr0) * ldK + cOff;
    pB = B + (col0 + rr0) * ldK + cOff;
  };
  auto stA = [&](int bi, int h, int kt) {
    char* d = smem + bi * 32768 + tid * 16;
    const short* s = pA + (long)kt * 64 + (long)(2 * h) * 64 * ldK;
    gload16(s, d + (2 * h) * 8192);
    gload16(s + (long)64 * ldK, d + (2 * h + 1) * 8192);
  };
  auto stB = [&](int bi, int h, int kt) {
    char* d = smem + 98304 + bi * 32768 + tid * 16;
    const short* s = pB + (long)kt * 64 + (long)(2 * h) * 64 * ldK;
    gload16(s, d + (2 * h) * 8192);
    gload16(s + (long)64 * ldK, d + (2 * h + 1) * 8192);
  };
  auto prologue = [&]() {
    stA(0, 0, 0); stA(0, 1, 0);
    stB(0, 0, 0); stB(0, 1, 0);
    stA(1, 0, 1); stA(1, 1, 1);    // queue: [A0(4), B0(4), A1(4)]
  };

  f32x4 zr = {0.f, 0.f, 0.f, 0.f};

  int r = loc;
  setTile(r);
  prologue();

  while (true) {
    f32x4 acc[8][4];
#pragma unroll
    for (int mi = 0; mi < 8; ++mi)
#pragma unroll
      for (int ni = 0; ni < 4; ++ni) acc[mi][ni] = zr;

    asm volatile("s_waitcnt vmcnt(4)" ::: "memory");  // A(0),B(0) landed
    asm volatile("s_barrier" ::: "memory");

    int ca = 0;
#pragma unroll 1
    for (int t = 0; t < iters; ++t) {
      const char* Ab = smem + ca * 32768;
      const char* Bb = smem + 98304 + (t & 1) * 32768;
      int na2 = (ca >= 1) ? ca - 1 : 2;   // (ca+2)%3: buffer for A(t+2)
      int nb1 = (t + 1) & 1;
      bf16x8 bF[4][2];

#pragma unroll
      for (int p = 0; p < 4; ++p) {
        if (p == 0) {
#pragma unroll
          for (int ni = 0; ni < 4; ++ni) {
            const char* base = Bb + (wc * 64 + ni * 16 + lrow) * 128;
            FragCast f0, f1;
            f0.i = *(const int4*)(base + csel0);
            f1.i = *(const int4*)(base + csel1);
            bF[ni][0] = f0.b; bF[ni][1] = f1.b;
          }
        }
        bf16x8 aF[2][2];
#pragma unroll
        for (int m2 = 0; m2 < 2; ++m2) {
          const char* base = Ab + (wr * 128 + p * 32 + m2 * 16 + lrow) * 128;
          FragCast f0, f1;
          f0.i = *(const int4*)(base + csel0);
          f1.i = *(const int4*)(base + csel1);
          aF[m2][0] = f0.b; aF[m2][1] = f1.b;
        }
        if (p == 0 && t + 1 < iters) stB(nb1, 0, t + 1);
        if (p == 1 && t + 1 < iters) stB(nb1, 1, t + 1);
        if (p == 2 && t + 2 < iters) stA(na2, 0, t + 2);
        if (p == 3) {
          if (t + 2 < iters) {
            stA(na2, 1, t + 2);
            asm volatile("s_waitcnt vmcnt(4)" ::: "memory");
          } else {
            asm volatile("s_waitcnt vmcnt(0)" ::: "memory");
          }
        }
        asm volatile("s_barrier" ::: "memory");
        __builtin_amdgcn_s_setprio(1);
#pragma unroll
        for (int k = 0; k < 2; ++k)
#pragma unroll
          for (int m2 = 0; m2 < 2; ++m2)
#pragma unroll
            for (int ni = 0; ni < 4; ++ni)
              acc[p * 2 + m2][ni] = __builtin_amdgcn_mfma_f32_16x16x32_bf16(
                  aF[m2][k], bF[ni][k], acc[p * 2 + m2][ni], 0, 0, 0);
        __builtin_amdgcn_s_setprio(0);
        // (post-MFMA barrier removed: waves may skew 1 phase -> overlap)
      }
      ca = (ca == 2) ? 0 : ca + 1;
    }

    // chain: issue next tile's prologue BEFORE epilogue stores
    long crow = row0, ccol = col0;
    r += 32;
    bool hasNext = (r < tilesPerXcd);
    if (hasNext) { setTile(r); prologue(); }

    // epilogue: C/D layout col=lane&15, row=(lane>>4)*4+reg  [m89]
#pragma unroll
    for (int mi = 0; mi < 8; ++mi)
#pragma unroll
      for (int ni = 0; ni < 4; ++ni)
#pragma unroll
        for (int j = 0; j < 4; ++j) {
          long grow = crow + wr * 128 + mi * 16 + lhi * 4 + j;
          long gcol = ccol + wc * 64 + ni * 16 + lrow;
          long idx = grow * ldo + gcol;
          float v = acc[mi][ni][j];
          if constexpr (MODE == 0) {
            outB[idx] = (short)f2bf_bits(v);
          } else {
            float g = bf2f(gbuf[idx]);
            float t2 = g * (1.f / (1.f + __expf(-g))) * v;   // silu(g)*u
            outB[idx] = (short)f2bf_bits(t2);
          }
        }
    if (!hasNext) break;
  }
}

// --------------------- down GEMM: same single-barrier-per-phase structure
__global__ __launch_bounds__(512, 2)
void gemm_down(const short* __restrict__ A, const short* __restrict__ B,
               float* outF, int nby, long ldK, int iters, long ldo) {
  extern __shared__ __align__(16) char smem[];

  int nwg = gridDim.x;
  int orig = blockIdx.x;
  int q = nwg >> 3, rr = nwg & 7;
  int xcd = orig & 7, loc = orig >> 3;
  int swz = (xcd < rr ? xcd * (q + 1) : rr * (q + 1) + (xcd - rr) * q) + loc;
  int by = swz % nby, bx = swz / nby;
  long row0 = (long)bx * 256, col0 = (long)by * 256;

  int tid = threadIdx.x;
  int l = tid & 63, wid = tid >> 6;
  int wr = wid >> 2, wc = wid & 3;
  int lrow = l & 15, lhi = l >> 4, md = lrow & 7;

  const short* aP[4]; const short* bP[4];
  int dst[4];
#pragma unroll
  for (int k = 0; k < 4; ++k) {
    int idx = tid + k * 512;
    int r = idx >> 3, c8 = idx & 7;
    aP[k] = A + (row0 + r) * ldK + (c8 ^ (r & 7)) * 8;
    bP[k] = B + (col0 + r) * ldK + (c8 ^ (r & 7)) * 8;
    dst[k] = idx * 16;
  }

  auto stageA_h = [&](int bi, int h) {
    char* d = smem + bi * 32768;
    gload16(aP[2 * h], d + dst[2 * h]);         aP[2 * h] += 64;
    gload16(aP[2 * h + 1], d + dst[2 * h + 1]); aP[2 * h + 1] += 64;
  };
  auto stageB_h = [&](int bi, int h) {
    char* d = smem + 98304 + bi * 32768;
    gload16(bP[2 * h], d + dst[2 * h]);         bP[2 * h] += 64;
    gload16(bP[2 * h + 1], d + dst[2 * h + 1]); bP[2 * h + 1] += 64;
  };

  f32x4 acc[8][4];
  f32x4 zr = {0.f, 0.f, 0.f, 0.f};
#pragma unroll
  for (int mi = 0; mi < 8; ++mi)
#pragma unroll
    for (int ni = 0; ni < 4; ++ni) acc[mi][ni] = zr;

  const int csel0 = (lhi ^ md) * 16;
  const int csel1 = ((4 + lhi) ^ md) * 16;

  stageA_h(0, 0); stageA_h(0, 1);
  stageB_h(0, 0); stageB_h(0, 1);
  stageA_h(1, 0); stageA_h(1, 1);
  asm volatile("s_waitcnt vmcnt(4)" ::: "memory");
  asm volatile("s_barrier" ::: "memory");

  int ca = 0;
#pragma unroll 1
  for (int t = 0; t < iters; ++t) {
    const char* Ab = smem + ca * 32768;
    const char* Bb = smem + 98304 + (t & 1) * 32768;
    int na2 = (ca >= 1) ? ca - 1 : 2;
    int nb1 = (t + 1) & 1;
    bf16x8 bF[4][2];

#pragma unroll
    for (int p = 0; p < 4; ++p) {
      if (p == 0) {
#pragma unroll
        for (int ni = 0; ni < 4; ++ni) {
          const char* base = Bb + (wc * 64 + ni * 16 + lrow) * 128;
          FragCast f0, f1;
          f0.i = *(const int4*)(base + csel0);
          f1.i = *(const int4*)(base + csel1);
          bF[ni][0] = f0.b; bF[ni][1] = f1.b;
        }
      }
      bf16x8 aF[2][2];
#pragma unroll
      for (int m2 = 0; m2 < 2; ++m2) {
        const char* base = Ab + (wr * 128 + p * 32 + m2 * 16 + lrow) * 128;
        FragCast f0, f1;
        f0.i = *(const int4*)(base + csel0);
        f1.i = *(const int4*)(base + csel1);
        aF[m2][0] = f0.b; aF[m2][1] = f1.b;
      }
      if (p == 0 && t + 1 < iters) stageB_h(nb1, 0);
      if (p == 1 && t + 1 < iters) stageB_h(nb1, 1);
      if (p == 2 && t + 2 < iters) stageA_h(na2, 0);
      if (p == 3) {
        if (t + 2 < iters) {
          stageA_h(na2, 1);
          asm volatile("s_waitcnt vmcnt(4)" ::: "memory");
        } else {
          asm volatile("s_waitcnt vmcnt(0)" ::: "memory");
        }
      }
      asm volatile("s_barrier" ::: "memory");
      __builtin_amdgcn_s_setprio(1);
#pragma unroll
      for (int k = 0; k < 2; ++k)
#pragma unroll
        for (int m2 = 0; m2 < 2; ++m2)
#pragma unroll
          for (int ni = 0; ni < 4; ++ni)
            acc[p * 2 + m2][ni] = __builtin_amdgcn_mfma_f32_16x16x32_bf16(
                aF[m2][k], bF[ni][k], acc[p * 2 + m2][ni], 0, 0, 0);
      __builtin_amdgcn_s_setprio(0);
      // (post-MFMA barrier removed)
    }
    ca = (ca == 2) ? 0 : ca + 1;
  }

#pragma unroll
  for (int mi = 0; mi < 8; ++mi)
#pragma unroll
    for (int ni = 0; ni < 4; ++ni)
#pragma unroll
      for (int j = 0; j < 4; ++j) {
        long grow = row0 + wr * 128 + mi * 16 + lhi * 4 + j;
        long gcol = col0 + wc * 64 + ni * 16 + lrow;
        outF[grow * ldo + gcol] = acc[mi][ni][j];
      }
}

// ---------------------------------------------------------------- launcher
extern "C" void kernel_launch(void* const* d_in, const int* in_sizes, int n_in,
                              void* d_out, int out_size, void* d_ws,
                              size_t ws_size, hipStream_t stream) {
  const float* x       = (const float*)d_in[0];
  const float* gate_w  = (const float*)d_in[1];
  const float* up_w    = (const float*)d_in[2];
  const float* down_w  = (const float*)d_in[3];
  const float* gate_wa = (const float*)d_in[4];
  const float* gate_wb = (const float*)d_in[5];
  const float* up_wa   = (const float*)d_in[6];
  const float* up_wb   = (const float*)d_in[7];
  const float* down_wa = (const float*)d_in[8];
  const float* down_wb = (const float*)d_in[9];
  const int*   seg     = (const int*)d_in[10];

  // ldK gate/up = 4096+128 = 4224 (iters=66); down ld = 11008+64 = 11072 (173)
  char* ws = (char*)d_ws;
  short* xg_pad = (short*)(ws);                   // [4096][4224]  34.6 MB
  short* wA     = (short*)(ws + 34603008);        // gate_w pad -> down_w pad
  short* wB     = (short*)(ws + 127598592);       // up_w pad     93.0 MB
  short* t_pad  = (short*)(ws + 220594176);       // [4096][11072] 90.7 MB

  const int LDS_G = 163840;   // A 3x32K + B 2x32K
  hipFuncSetAttribute(reinterpret_cast<const void*>(&gemm_gu<0>),
                      hipFuncAttributeMaxDynamicSharedMemorySize, LDS_G);
  hipFuncSetAttribute(reinterpret_cast<const void*>(&gemm_gu<1>),
                      hipFuncAttributeMaxDynamicSharedMemorySize, LDS_G);
  hipFuncSetAttribute(reinterpret_cast<const void*>(&gemm_down),
                      hipFuncAttributeMaxDynamicSharedMemorySize, LDS_G);

  // bf16 padded operand build (cvt_pad zero-fills the 128-col LoRA tail of
  // the weight matrices; build_wbT then overwrites its 64-col band)
  cvt_pad<<<T_TOK, 256, 0, stream>>>(x, xg_pad, 512, 512, HID, 4224);
  cvt_pad<<<IMD, 256, 0, stream>>>(gate_w, wA, 512, 528, HID, 4224);
  cvt_pad<<<IMD, 256, 0, stream>>>(up_w, wB, 512, 528, HID, 4224);
  build_wbT_pad<<<dim3(43, 64), 256, 0, stream>>>(gate_wb, wA, IMD, 4224, 4096);
  build_wbT_pad<<<dim3(43, 64), 256, 0, stream>>>(up_wb, wB, IMD, 4224, 4160);
  lora_proj<HID, 2><<<T_TOK, 256, 0, stream>>>(
      xg_pad, 4224, gate_wa, up_wa, seg, xg_pad + 4096, 4224, xg_pad + 4160,
      4224);

  // gate (persistent, 1 block/CU): t_pad = x @ gate_w^T + lora_g
  gemm_gu<0><<<256, 512, LDS_G, stream>>>(xg_pad, wA, nullptr, t_pad,
                                          86, 4224, 66, 11072);
  // up (persistent): t_pad = silu(t_pad) * (x @ up_w^T + lora_u), in place
  gemm_gu<1><<<256, 512, LDS_G, stream>>>(xg_pad, wB, t_pad, t_pad,
                                          86, 4224, 66, 11072);

  // down operand build (wA region free after gate GEMM)
  cvt_pad<<<T_TOK, 256, 0, stream>>>(down_w, wA, 1376, 1376, IMD, 11072);
  build_wbT_pad<<<dim3(16, 64), 256, 0, stream>>>(down_wb, wA, HID, 11072,
                                                  IMD);
  lora_proj<IMD, 1><<<T_TOK, 256, 0, stream>>>(
      t_pad, 11072, down_wa, nullptr, seg, t_pad + IMD, 11072, nullptr, 64);

  // down: out = t @ down_w^T + lora   [M=4096, N=4096, K'=11072]
  gemm_down<<<16 * 16, 512, LDS_G, stream>>>(t_pad, wA, (float*)d_out, 16,
                                             11072, 173, 4096);
}